// Round 9
// baseline (187.975 us; speedup 1.0000x reference)
//
#include <hip/hip_runtime.h>
#include <hip/hip_bf16.h>

typedef float f2 __attribute__((ext_vector_type(2)));

// fast sigmoid / tanh via native v_exp_f32 + v_rcp_f32 (~1e-6 rel err vs threshold 7.8e-4)
__device__ __forceinline__ float sigf(float x) {
  return __builtin_amdgcn_rcpf(1.0f + __expf(-x));
}
__device__ __forceinline__ float tanh_fast(float x) {
  return fmaf(-2.0f, __builtin_amdgcn_rcpf(1.0f + __expf(2.0f * x)), 1.0f);
}
template<int CTRL>
__device__ __forceinline__ float dppf(float v) {
  return __builtin_bit_cast(float,
      __builtin_amdgcn_mov_dpp(__builtin_bit_cast(int, v), CTRL, 0xf, 0xf, false));
}
// xor8 within each 16-lane row: DPP row_ror:8 (0x128). Lane k <-> k^8. (DPP verified on HW in R7.)

// B=16384, T=64, H=8. 16 lanes per element: lane = (half,j); half=0 owns gates (i,f),
// half=1 owns (g,o) of unit j. 4096 waves = 4 waves/SIMD (2x R5's TLP), per-lane work ~halved.
// Block = 256 threads = 16 elements; grid = 1024 blocks = 4 blocks/CU.
__launch_bounds__(256, 4)
__global__ void lstm_fused16(
    const int* __restrict__ x,
    const float* __restrict__ e1, const float* __restrict__ e2,
    const float* __restrict__ e3, const float* __restrict__ e4,
    const float* __restrict__ e5, const float* __restrict__ e6,
    const float* __restrict__ e7, const float* __restrict__ e8,
    const float* __restrict__ W_ih0, const float* __restrict__ W_hh0,
    const float* __restrict__ b_ih0, const float* __restrict__ b_hh0,
    const float* __restrict__ W_ih1, const float* __restrict__ W_hh1,
    const float* __restrict__ b_ih1, const float* __restrict__ b_hh1,
    const float* __restrict__ fc6_w, const float* __restrict__ fc6_b,
    const float* __restrict__ fc7_w, const float* __restrict__ fc7_b,
    const float* __restrict__ fc1_w, const float* __restrict__ fc1_b,
    const float* __restrict__ fc2_w, const float* __restrict__ fc2_b,
    const float* __restrict__ fc3_w, const float* __restrict__ fc3_b,
    float* __restrict__ out)
{
  // Fused embedding x W_ih0 tables, feature pairs (0,1) and (4,5) combined:
  // rows: f01:0(4) f2:4(21) f3:25(22) f45:47(10) f6:57(22) f7:79(24) = 103 rows.
  // Row layout: 32 floats = [lane16][2]: entry m: L=m>>1, c=m&1 -> gate ((L>>3)*2+c)*8+(L&7).
  __shared__ __align__(16) float sTf[103*32];
  __shared__ float sW3s[65];                 // sW3s[0]=0, sW3s[t+1]=fc3_w[t]
  __shared__ __align__(16) float sH0[128];   // 16 elem x 8 units
  __shared__ __align__(16) float sH1[128];

  const int tid = threadIdx.x;

  // ---- build fused tables ----
  {
    for (int idx = tid; idx < 4*32; idx += 256) {        // f01
      int r = idx>>5, m = idx&31, L = m>>1, cg = m&1;
      int g = ((L>>3)*2 + cg)*8 + (L&7);
      float s = e1[r>>1]*W_ih0[g*16+0] + e2[r&1]*W_ih0[g*16+1]
              + b_ih0[g] + b_hh0[g];
      sTf[r*32 + m] = s;
    }
    for (int idx = tid; idx < 21*32; idx += 256) {       // f2 (e3, cols 2-4)
      int r = idx>>5, m = idx&31, L = m>>1, cg = m&1;
      int g = ((L>>3)*2 + cg)*8 + (L&7);
      float s = 0.f;
      #pragma unroll
      for (int d = 0; d < 3; ++d) s += e3[r*3+d]*W_ih0[g*16+2+d];
      sTf[(4+r)*32 + m] = s;
    }
    for (int idx = tid; idx < 22*32; idx += 256) {       // f3 (e4, cols 5-7)
      int r = idx>>5, m = idx&31, L = m>>1, cg = m&1;
      int g = ((L>>3)*2 + cg)*8 + (L&7);
      float s = 0.f;
      #pragma unroll
      for (int d = 0; d < 3; ++d) s += e4[r*3+d]*W_ih0[g*16+5+d];
      sTf[(25+r)*32 + m] = s;
    }
    for (int idx = tid; idx < 10*32; idx += 256) {       // f45
      int r = idx>>5, m = idx&31, L = m>>1, cg = m&1;
      int g = ((L>>3)*2 + cg)*8 + (L&7);
      float s = e5[r>>1]*W_ih0[g*16+8] + e6[r&1]*W_ih0[g*16+9];
      sTf[(47+r)*32 + m] = s;
    }
    for (int idx = tid; idx < 22*32; idx += 256) {       // f6 (e7, cols 10-12)
      int r = idx>>5, m = idx&31, L = m>>1, cg = m&1;
      int g = ((L>>3)*2 + cg)*8 + (L&7);
      float s = 0.f;
      #pragma unroll
      for (int d = 0; d < 3; ++d) s += e7[r*3+d]*W_ih0[g*16+10+d];
      sTf[(57+r)*32 + m] = s;
    }
    for (int idx = tid; idx < 24*32; idx += 256) {       // f7 (e8, cols 13-15)
      int r = idx>>5, m = idx&31, L = m>>1, cg = m&1;
      int g = ((L>>3)*2 + cg)*8 + (L&7);
      float s = 0.f;
      #pragma unroll
      for (int d = 0; d < 3; ++d) s += e8[r*3+d]*W_ih0[g*16+13+d];
      sTf[(79+r)*32 + m] = s;
    }
    if (tid < 64) sW3s[tid+1] = fc3_w[tid];
    if (tid == 64) sW3s[0] = 0.f;
  }
  __syncthreads();

  const int lane16 = tid & 15;
  const int j      = tid & 7;
  const int half   = (tid >> 3) & 1;         // 0: gates (i,f); 1: gates (g,o)
  const int e      = tid >> 4;               // element within block
  const int b      = (blockIdx.x << 4) + e;

  const int p = (half*2)*8 + j;              // own p-gate row (i or g)
  const int q = p + 8;                       // own q-gate row (f or o)

  // per-lane weight pairs (p,q) for the three matvec matrices
  f2 w0[8], i1[8], r1[8];
  #pragma unroll
  for (int k = 0; k < 8; ++k) {
    w0[k] = (f2){W_hh0[p*8+k], W_hh0[q*8+k]};
    i1[k] = (f2){W_ih1[p*8+k], W_ih1[q*8+k]};
    r1[k] = (f2){W_hh1[p*8+k], W_hh1[q*8+k]};
  }
  const f2 b1 = {b_ih1[p] + b_hh1[p], b_ih1[q] + b_hh1[q]};

  // collapsed FC heads (lane-uniform)
  f2 uvk[8];
  float f7[4], f2c[4];
  #pragma unroll
  for (int qq = 0; qq < 4; ++qq) { f7[qq] = fc7_w[qq]; f2c[qq] = fc2_w[qq]; }
  #pragma unroll
  for (int k = 0; k < 8; ++k) {
    float s1 = 0.f, s2 = 0.f;
    #pragma unroll
    for (int qq = 0; qq < 4; ++qq) {
      s1 += f7[qq]  * fc6_w[qq*8+k];
      s2 += f2c[qq] * fc1_w[qq*8+k];
    }
    uvk[k] = (f2){s1, s2};
  }
  float cth = fc7_b[0], chh = fc2_b[0];
  #pragma unroll
  for (int qq = 0; qq < 4; ++qq) { cth += f7[qq]*fc6_b[qq]; chh += f2c[qq]*fc1_b[qq]; }
  const f2 cc = {cth, chh};
  const float fc3b = fc3_b[0];

  // uniform-activation constants: p-gate is sigmoid (half0) or tanh via 2*sig(2x)-1 (half1)
  const float aph = half ? 2.f : 1.f;
  const float sph = half ? 2.f : 1.f;
  const float tph = half ? -1.f : 0.f;

  float h0x[8], h1x[8];
  #pragma unroll
  for (int k = 0; k < 8; ++k) { h0x[k] = 0.f; h1x[k] = 0.f; }
  float c0 = 0.f, c1 = 0.f, acc = 0.f;

  const int4* xp = (const int4*)(x + (size_t)b * 512);
  const f2* tf2 = (const f2*)sTf;
  const float4* ph0 = (const float4*)&sH0[e*8];
  const float4* ph1 = (const float4*)&sH1[e*8];

  // prologue: gathers for t=0; ids for t=1
  int4 ia = xp[0], ib = xp[1];
  f2 G01 = tf2[(    ia.x*2 + ia.y)*16 + lane16];
  f2 G2  = tf2[( 4 + ia.z)*16 + lane16];
  f2 G3  = tf2[(25 + ia.w)*16 + lane16];
  f2 G45 = tf2[(47 + ib.x*2 + ib.y)*16 + lane16];
  f2 G6  = tf2[(57 + ib.z)*16 + lane16];
  f2 G7  = tf2[(79 + ib.w)*16 + lane16];
  int4 na = xp[2], nb = xp[3];

  #pragma unroll 1
  for (int t = 0; t < 64; ++t) {
    const float w3p = sW3s[t];

    // (1) l0 gate-pair sum from prefetched gathers
    f2 g0 = ((G01 + G2) + (G3 + G45)) + (G6 + G7);

    // (2) issue gathers for t+1; prefetch ids t+2
    G01 = tf2[(    na.x*2 + na.y)*16 + lane16];
    G2  = tf2[( 4 + na.z)*16 + lane16];
    G3  = tf2[(25 + na.w)*16 + lane16];
    G45 = tf2[(47 + nb.x*2 + nb.y)*16 + lane16];
    G6  = tf2[(57 + nb.z)*16 + lane16];
    G7  = tf2[(79 + nb.w)*16 + lane16];
    { const int tn = (2*t + 4 <= 126) ? (2*t + 4) : 126; na = xp[tn]; nb = xp[tn+1]; }

    // (3) l0 matvec
    #pragma unroll
    for (int k = 0; k < 8; ++k)
      g0 = __builtin_elementwise_fma(w0[k], (f2)(h0x[k]), g0);

    // (4) l0 activations (uniform across halves) + pair exchange via DPP xor8
    float yp = fmaf(sph, sigf(g0.x * aph), tph);   // half0: sig(i); half1: tanh(g)
    float yq = sigf(g0.y);                         // half0: sig(f); half1: sig(o)
    float xpv = dppf<0x128>(yp);
    float xqv = dppf<0x128>(yq);
    float itg = yp * xpv;                          // si*tg (symmetric under swap)
    float sfv = half ? xqv : yq;
    float sov = half ? yq : xqv;
    c0 = fmaf(sfv, c0, itg);
    float h0 = sov * tanh_fast(c0);                // pair lanes identical

    // (5) broadcast h0 to the element's 16 lanes (pair writes same value/addr)
    sH0[e*8 + j] = h0;

    // (6) fill h0 round-trip: FC(t-1) + l1 recurrent matvec on h1x
    f2 thf = cc, g1 = b1;
    #pragma unroll
    for (int k = 0; k < 8; ++k) {
      f2 hb = (f2)(h1x[k]);
      thf = __builtin_elementwise_fma(uvk[k], hb, thf);
      g1  = __builtin_elementwise_fma(r1[k],  hb, g1);
    }
    acc = fmaf(thf.x * thf.y, w3p, acc);

    // (7) read h0 vector back
    { float4 lo = ph0[0], hi = ph0[1];
      h0x[0]=lo.x; h0x[1]=lo.y; h0x[2]=lo.z; h0x[3]=lo.w;
      h0x[4]=hi.x; h0x[5]=hi.y; h0x[6]=hi.z; h0x[7]=hi.w; }

    // (8) l1 input matvec
    #pragma unroll
    for (int k = 0; k < 8; ++k)
      g1 = __builtin_elementwise_fma(i1[k], (f2)(h0x[k]), g1);

    // (9) l1 activations + pair exchange
    float yp1 = fmaf(sph, sigf(g1.x * aph), tph);
    float yq1 = sigf(g1.y);
    float xp1 = dppf<0x128>(yp1);
    float xq1 = dppf<0x128>(yq1);
    float itg1 = yp1 * xp1;
    float sf1 = half ? xq1 : yq1;
    float so1 = half ? yq1 : xq1;
    c1 = fmaf(sf1, c1, itg1);
    float h1 = so1 * tanh_fast(c1);

    // (10) broadcast h1 (read covered by next iteration's front half)
    sH1[e*8 + j] = h1;
    { float4 lo = ph1[0], hi = ph1[1];
      h1x[0]=lo.x; h1x[1]=lo.y; h1x[2]=lo.z; h1x[3]=lo.w;
      h1x[4]=hi.x; h1x[5]=hi.y; h1x[6]=hi.z; h1x[7]=hi.w; }
  }

  // epilogue: FC for t=63
  {
    f2 thf = cc;
    #pragma unroll
    for (int k = 0; k < 8; ++k)
      thf = __builtin_elementwise_fma(uvk[k], (f2)(h1x[k]), thf);
    acc = fmaf(thf.x * thf.y, sW3s[64], acc);
  }

  if (lane16 == 0) out[b] = acc + fc3b;
}

extern "C" void kernel_launch(void* const* d_in, const int* in_sizes, int n_in,
                              void* d_out, int out_size, void* d_ws, size_t ws_size,
                              hipStream_t stream) {
  const int* x = (const int*)d_in[0];
  const float *E1=(const float*)d_in[1],  *E2=(const float*)d_in[2],
              *E3=(const float*)d_in[3],  *E4=(const float*)d_in[4],
              *E5=(const float*)d_in[5],  *E6=(const float*)d_in[6],
              *E7=(const float*)d_in[7],  *E8=(const float*)d_in[8];
  const float *Wih0=(const float*)d_in[9],  *Whh0=(const float*)d_in[10],
              *bih0=(const float*)d_in[11], *bhh0=(const float*)d_in[12],
              *Wih1=(const float*)d_in[13], *Whh1=(const float*)d_in[14],
              *bih1=(const float*)d_in[15], *bhh1=(const float*)d_in[16],
              *fc6w=(const float*)d_in[17], *fc6b=(const float*)d_in[18],
              *fc7w=(const float*)d_in[19], *fc7b=(const float*)d_in[20],
              *fc1w=(const float*)d_in[21], *fc1b=(const float*)d_in[22],
              *fc2w=(const float*)d_in[23], *fc2b=(const float*)d_in[24],
              *fc3w=(const float*)d_in[25], *fc3b=(const float*)d_in[26];

  lstm_fused16<<<1024, 256, 0, stream>>>(
      x, E1,E2,E3,E4,E5,E6,E7,E8,
      Wih0, Whh0, bih0, bhh0, Wih1, Whh1, bih1, bhh1,
      fc6w, fc6b, fc7w, fc7b, fc1w, fc1b, fc2w, fc2b, fc3w, fc3b,
      (float*)d_out);
}

// Round 10
// 176.390 us; speedup vs baseline: 1.0657x; 1.0657x over previous
//
#include <hip/hip_runtime.h>
#include <hip/hip_bf16.h>

typedef float f2 __attribute__((ext_vector_type(2)));

// Pre-scaled activations: gate pre-activations carry a folded ±log2e factor so
// no runtime multiply is needed before v_exp_f32 (which computes 2^x natively).
__device__ __forceinline__ float sig_n(float y) {   // y = -log2e·x  ->  sigmoid(x)
  return __builtin_amdgcn_rcpf(1.0f + __builtin_exp2f(y));
}
__device__ __forceinline__ float tanh_p(float y) {  // y = 2·log2e·x ->  tanh(x)
  return fmaf(-2.0f, __builtin_amdgcn_rcpf(1.0f + __builtin_exp2f(y)), 1.0f);
}

#define NL (-1.44269504088896340736f)   // -log2(e)
#define TL ( 2.88539008177792681472f)   // 2·log2(e)

// B=16384, T=64, H=8. 8 lanes per batch element (lane j = hidden unit j).
// Block = 256 threads = 32 elements; grid = 512 blocks = 2 blocks/CU (2 waves/SIMD).
__launch_bounds__(256, 2)
__global__ void lstm_fused(
    const int* __restrict__ x,
    const float* __restrict__ e1, const float* __restrict__ e2,
    const float* __restrict__ e3, const float* __restrict__ e4,
    const float* __restrict__ e5, const float* __restrict__ e6,
    const float* __restrict__ e7, const float* __restrict__ e8,
    const float* __restrict__ W_ih0, const float* __restrict__ W_hh0,
    const float* __restrict__ b_ih0, const float* __restrict__ b_hh0,
    const float* __restrict__ W_ih1, const float* __restrict__ W_hh1,
    const float* __restrict__ b_ih1, const float* __restrict__ b_hh1,
    const float* __restrict__ fc6_w, const float* __restrict__ fc6_b,
    const float* __restrict__ fc7_w, const float* __restrict__ fc7_b,
    const float* __restrict__ fc1_w, const float* __restrict__ fc1_b,
    const float* __restrict__ fc2_w, const float* __restrict__ fc2_b,
    const float* __restrict__ fc3_w, const float* __restrict__ fc3_b,
    float* __restrict__ out)
{
  // Fused embedding×W_ih0 tables with feature pairs (0,1) and (4,5) merged:
  // groups f01:0(4) f2:4(21) f3:25(22) f45:47(10) f6:57(22) f7:79(24) = 103 rows.
  // Row layout: 32 floats = [j][q], q: 0=i,1=f,2=g,3=o -> float4 per (row, j).
  // All entries pre-scaled by NL (i,f,o) or TL (g); biases folded into f01.
  __shared__ __align__(16) float sTf[103*32];
  __shared__ float sW3s[65];   // sW3s[0]=0, sW3s[t+1]=fc3_w[t]  (deferred-FC weight)
  __shared__ __align__(16) float sH0[256];
  __shared__ __align__(16) float sH1[256];

  const int tid = threadIdx.x;

  // ---- build fused input tables in LDS (one-time) ----
  {
    for (int idx = tid; idx < 4*32; idx += 256) {        // f01 (e1,e2; cols 0,1) + biases
      int v = idx >> 5, m = idx & 31, jj = m >> 2, q = m & 3, g = q*8 + jj;
      float s = e1[v>>1]*W_ih0[g*16+0] + e2[v&1]*W_ih0[g*16+1]
              + b_ih0[g] + b_hh0[g];
      sTf[v*32 + m] = s * ((q==2)? TL : NL);
    }
    for (int idx = tid; idx < 21*32; idx += 256) {       // f2 (e3; cols 2-4)
      int v = idx >> 5, m = idx & 31, jj = m >> 2, q = m & 3, g = q*8 + jj;
      float s = 0.f;
      #pragma unroll
      for (int d = 0; d < 3; ++d) s += e3[v*3+d]*W_ih0[g*16+2+d];
      sTf[(4+v)*32 + m] = s * ((q==2)? TL : NL);
    }
    for (int idx = tid; idx < 22*32; idx += 256) {       // f3 (e4; cols 5-7)
      int v = idx >> 5, m = idx & 31, jj = m >> 2, q = m & 3, g = q*8 + jj;
      float s = 0.f;
      #pragma unroll
      for (int d = 0; d < 3; ++d) s += e4[v*3+d]*W_ih0[g*16+5+d];
      sTf[(25+v)*32 + m] = s * ((q==2)? TL : NL);
    }
    for (int idx = tid; idx < 10*32; idx += 256) {       // f45 (e5,e6; cols 8,9)
      int v = idx >> 5, m = idx & 31, jj = m >> 2, q = m & 3, g = q*8 + jj;
      float s = e5[v>>1]*W_ih0[g*16+8] + e6[v&1]*W_ih0[g*16+9];
      sTf[(47+v)*32 + m] = s * ((q==2)? TL : NL);
    }
    for (int idx = tid; idx < 22*32; idx += 256) {       // f6 (e7; cols 10-12)
      int v = idx >> 5, m = idx & 31, jj = m >> 2, q = m & 3, g = q*8 + jj;
      float s = 0.f;
      #pragma unroll
      for (int d = 0; d < 3; ++d) s += e7[v*3+d]*W_ih0[g*16+10+d];
      sTf[(57+v)*32 + m] = s * ((q==2)? TL : NL);
    }
    for (int idx = tid; idx < 24*32; idx += 256) {       // f7 (e8; cols 13-15)
      int v = idx >> 5, m = idx & 31, jj = m >> 2, q = m & 3, g = q*8 + jj;
      float s = 0.f;
      #pragma unroll
      for (int d = 0; d < 3; ++d) s += e8[v*3+d]*W_ih0[g*16+13+d];
      sTf[(79+v)*32 + m] = s * ((q==2)? TL : NL);
    }
    if (tid < 64) sW3s[tid+1] = fc3_w[tid];
    if (tid == 64) sW3s[0] = 0.f;
  }
  __syncthreads();

  const int j = tid & 7;                         // hidden unit owned by this lane
  const int b = (blockIdx.x << 5) + (tid >> 3);  // batch element

  sH1[tid] = 0.f;  // pre-init: read at top of t=0 before first write (in-wave ordering)

  // ---- per-lane recurrent weights packed as float2 gate-pairs, pre-scaled ----
  f2 wIF0[8], wGO0[8], iIF1[8], iGO1[8], rIF1[8], rGO1[8];
  {
    const float4* P;
    float4 I0,I1,F0,F1,G0_,G1_,O0,O1;
    #define LOADROWS(M) \
      P = (const float4*)(M); \
      I0 = P[(0*8+j)*2]; I1 = P[(0*8+j)*2+1]; \
      F0 = P[(1*8+j)*2]; F1 = P[(1*8+j)*2+1]; \
      G0_ = P[(2*8+j)*2]; G1_ = P[(2*8+j)*2+1]; \
      O0 = P[(3*8+j)*2]; O1 = P[(3*8+j)*2+1];
    #define PACK(dIF, dGO) \
      dIF[0]=(f2){I0.x,F0.x}; dIF[1]=(f2){I0.y,F0.y}; dIF[2]=(f2){I0.z,F0.z}; dIF[3]=(f2){I0.w,F0.w}; \
      dIF[4]=(f2){I1.x,F1.x}; dIF[5]=(f2){I1.y,F1.y}; dIF[6]=(f2){I1.z,F1.z}; dIF[7]=(f2){I1.w,F1.w}; \
      dGO[0]=(f2){G0_.x,O0.x}; dGO[1]=(f2){G0_.y,O0.y}; dGO[2]=(f2){G0_.z,O0.z}; dGO[3]=(f2){G0_.w,O0.w}; \
      dGO[4]=(f2){G1_.x,O1.x}; dGO[5]=(f2){G1_.y,O1.y}; dGO[6]=(f2){G1_.z,O1.z}; dGO[7]=(f2){G1_.w,O1.w};
    LOADROWS(W_hh0); PACK(wIF0, wGO0);
    LOADROWS(W_ih1); PACK(iIF1, iGO1);
    LOADROWS(W_hh1); PACK(rIF1, rGO1);
    #undef LOADROWS
    #undef PACK
    #pragma unroll
    for (int k = 0; k < 8; ++k) {
      wIF0[k] *= (f2){NL,NL};  wGO0[k] *= (f2){TL,NL};
      iIF1[k] *= (f2){NL,NL};  iGO1[k] *= (f2){TL,NL};
      rIF1[k] *= (f2){NL,NL};  rGO1[k] *= (f2){TL,NL};
    }
  }
  const f2 bIF1 = {NL*(b_ih1[j]    + b_hh1[j]),    NL*(b_ih1[8+j]  + b_hh1[8+j])};
  const f2 bGO1 = {TL*(b_ih1[16+j] + b_hh1[16+j]), NL*(b_ih1[24+j] + b_hh1[24+j])};

  // ---- collapsed FC heads (theta,h) packed (unscaled — consume raw h) ----
  f2 uvk[8];
  float f7[4], f2c[4];
  #pragma unroll
  for (int q = 0; q < 4; ++q) { f7[q] = fc7_w[q]; f2c[q] = fc2_w[q]; }
  #pragma unroll
  for (int k = 0; k < 8; ++k) {
    float s1 = 0.f, s2 = 0.f;
    #pragma unroll
    for (int q = 0; q < 4; ++q) {
      s1 += f7[q]  * fc6_w[q*8+k];
      s2 += f2c[q] * fc1_w[q*8+k];
    }
    uvk[k] = (f2){s1, s2};
  }
  float cth = fc7_b[0], chh = fc2_b[0];
  #pragma unroll
  for (int q = 0; q < 4; ++q) { cth += f7[q]*fc6_b[q]; chh += f2c[q]*fc1_b[q]; }
  const f2 cc = {cth, chh};
  const float fc3b = fc3_b[0];

  // ---- state ----
  float h0s[8];
  #pragma unroll
  for (int k = 0; k < 8; ++k) h0s[k] = 0.f;
  float c0 = 0.f, c1 = 0.f, acc = 0.f;

  const int4* xp = (const int4*)(x + (size_t)b * 512);  // [T][8] ids, 2 int4 per step
  int4 ia = xp[0], ib = xp[1];
  const float4* tf4 = (const float4*)sTf;
  const float4* ph0 = (const float4*)&sH0[tid & ~7];
  const float4* ph1 = (const float4*)&sH1[tid & ~7];

  #pragma unroll 1
  for (int t = 0; t < 64; ++t) {
    // (1) issue read of h1(t-1) early — latency hides under gather + layer-0 work
    float4 h1A = ph1[0], h1B = ph1[1];
    float h1s[8] = {h1A.x,h1A.y,h1A.z,h1A.w,h1B.x,h1B.y,h1B.z,h1B.w};

    // (2) prefetch next step's ids
    const int tn = (t < 63) ? (2*t + 2) : 126;
    int4 na = xp[tn], nb = xp[tn+1];
    const float w3p = sW3s[t];   // FC of step t-1 folded into step t (0 at t=0)

    // (3) layer-0 input gates: 6 merged-table gathers (bias + exp2-scale pre-folded)
    float4 g0 = tf4[(     ia.x*2 + ia.y)*8 + j];   // f01
    float4 g1 = tf4[( 4 + ia.z)*8 + j];            // f2
    float4 g2 = tf4[(25 + ia.w)*8 + j];            // f3
    float4 g3 = tf4[(47 + ib.x*2 + ib.y)*8 + j];   // f45
    float4 g4 = tf4[(57 + ib.z)*8 + j];            // f6
    float4 g5 = tf4[(79 + ib.w)*8 + j];            // f7
    f2 gIF = (((f2){g0.x,g0.y} + (f2){g1.x,g1.y}) + ((f2){g2.x,g2.y} + (f2){g3.x,g3.y}))
           + ((f2){g4.x,g4.y} + (f2){g5.x,g5.y});
    f2 gGO = (((f2){g0.z,g0.w} + (f2){g1.z,g1.w}) + ((f2){g2.z,g2.w} + (f2){g3.z,g3.w}))
           + ((f2){g4.z,g4.w} + (f2){g5.z,g5.w});

    // (4) layer-0 recurrence (packed, pre-scaled), activations, write h0
    #pragma unroll
    for (int k = 0; k < 8; ++k) {
      f2 hb = (f2)(h0s[k]);
      gIF = __builtin_elementwise_fma(wIF0[k], hb, gIF);
      gGO = __builtin_elementwise_fma(wGO0[k], hb, gGO);
    }
    float si = sig_n(gIF.x), sf = sig_n(gIF.y), tg = tanh_p(gGO.x), so = sig_n(gGO.y);
    c0 = fmaf(sf, c0, si * tg);
    float h0 = so * tanh_p(c0 * TL);
    sH0[tid] = h0;  // in-wave broadcast (8-lane groups never cross a wave)

    // (5) work independent of the h0 read: W_hh1*h1(t-1) and deferred FC(t-1)
    f2 GIF = bIF1, GGO = bGO1, thf = cc;
    #pragma unroll
    for (int k = 0; k < 8; ++k) {
      f2 hb = (f2)(h1s[k]);
      GIF = __builtin_elementwise_fma(rIF1[k], hb, GIF);
      GGO = __builtin_elementwise_fma(rGO1[k], hb, GGO);
      thf = __builtin_elementwise_fma(uvk[k],  hb, thf);
    }
    acc = fmaf(thf.x * thf.y, w3p, acc);

    // (6) read h0 back (exchange across the 8-lane group)
    {
      float4 lo = ph0[0], hi = ph0[1];
      h0s[0]=lo.x; h0s[1]=lo.y; h0s[2]=lo.z; h0s[3]=lo.w;
      h0s[4]=hi.x; h0s[5]=hi.y; h0s[6]=hi.z; h0s[7]=hi.w;
    }

    // (7) layer-1 input matvec, activations, write h1 (read deferred to t+1)
    #pragma unroll
    for (int k = 0; k < 8; ++k) {
      f2 hb = (f2)(h0s[k]);
      GIF = __builtin_elementwise_fma(iIF1[k], hb, GIF);
      GGO = __builtin_elementwise_fma(iGO1[k], hb, GGO);
    }
    float si1 = sig_n(GIF.x), sf1 = sig_n(GIF.y), tg1 = tanh_p(GGO.x), so1 = sig_n(GGO.y);
    c1 = fmaf(sf1, c1, si1 * tg1);
    float h1 = so1 * tanh_p(c1 * TL);
    sH1[tid] = h1;

    ia = na; ib = nb;
  }

  // epilogue: FC for t=63
  {
    float4 h1A = ph1[0], h1B = ph1[1];
    float h1s[8] = {h1A.x,h1A.y,h1A.z,h1A.w,h1B.x,h1B.y,h1B.z,h1B.w};
    f2 thf = cc;
    #pragma unroll
    for (int k = 0; k < 8; ++k)
      thf = __builtin_elementwise_fma(uvk[k], (f2)(h1s[k]), thf);
    acc = fmaf(thf.x * thf.y, sW3s[64], acc);
  }

  if (j == 0) out[b] = acc + fc3b;
}

extern "C" void kernel_launch(void* const* d_in, const int* in_sizes, int n_in,
                              void* d_out, int out_size, void* d_ws, size_t ws_size,
                              hipStream_t stream) {
  const int* x = (const int*)d_in[0];
  const float *E1=(const float*)d_in[1],  *E2=(const float*)d_in[2],
              *E3=(const float*)d_in[3],  *E4=(const float*)d_in[4],
              *E5=(const float*)d_in[5],  *E6=(const float*)d_in[6],
              *E7=(const float*)d_in[7],  *E8=(const float*)d_in[8];
  const float *Wih0=(const float*)d_in[9],  *Whh0=(const float*)d_in[10],
              *bih0=(const float*)d_in[11], *bhh0=(const float*)d_in[12],
              *Wih1=(const float*)d_in[13], *Whh1=(const float*)d_in[14],
              *bih1=(const float*)d_in[15], *bhh1=(const float*)d_in[16],
              *fc6w=(const float*)d_in[17], *fc6b=(const float*)d_in[18],
              *fc7w=(const float*)d_in[19], *fc7b=(const float*)d_in[20],
              *fc1w=(const float*)d_in[21], *fc1b=(const float*)d_in[22],
              *fc2w=(const float*)d_in[23], *fc2b=(const float*)d_in[24],
              *fc3w=(const float*)d_in[25], *fc3b=(const float*)d_in[26];

  lstm_fused<<<512, 256, 0, stream>>>(
      x, E1,E2,E3,E4,E5,E6,E7,E8,
      Wih0, Whh0, bih0, bhh0, Wih1, Whh1, bih1, bhh1,
      fc6w, fc6b, fc7w, fc7b, fc1w, fc1b, fc2w, fc2b, fc3w, fc3b,
      (float*)d_out);
}

// Round 11
// 172.085 us; speedup vs baseline: 1.0923x; 1.0250x over previous
//
#include <hip/hip_runtime.h>
#include <hip/hip_bf16.h>

typedef float f2 __attribute__((ext_vector_type(2)));

// fast sigmoid / tanh via native v_exp_f32 + v_rcp_f32 (~1e-6 rel err vs threshold 7.8e-4)
__device__ __forceinline__ float sigf(float x) {
  return __builtin_amdgcn_rcpf(1.0f + __expf(-x));
}
__device__ __forceinline__ float tanh_fast(float x) {
  return fmaf(-2.0f, __builtin_amdgcn_rcpf(1.0f + __expf(2.0f * x)), 1.0f);
}

// B=16384, T=64, H=8. 8 lanes per batch element (lane j = hidden unit j).
// Block = 256 threads = 32 elements; grid = 512 blocks = 2 blocks/CU (8 waves/CU).
__launch_bounds__(256, 2)
__global__ void lstm_fused(
    const int* __restrict__ x,
    const float* __restrict__ e1, const float* __restrict__ e2,
    const float* __restrict__ e3, const float* __restrict__ e4,
    const float* __restrict__ e5, const float* __restrict__ e6,
    const float* __restrict__ e7, const float* __restrict__ e8,
    const float* __restrict__ W_ih0, const float* __restrict__ W_hh0,
    const float* __restrict__ b_ih0, const float* __restrict__ b_hh0,
    const float* __restrict__ W_ih1, const float* __restrict__ W_hh1,
    const float* __restrict__ b_ih1, const float* __restrict__ b_hh1,
    const float* __restrict__ fc6_w, const float* __restrict__ fc6_b,
    const float* __restrict__ fc7_w, const float* __restrict__ fc7_b,
    const float* __restrict__ fc1_w, const float* __restrict__ fc1_b,
    const float* __restrict__ fc2_w, const float* __restrict__ fc2_b,
    const float* __restrict__ fc3_w, const float* __restrict__ fc3_b,
    float* __restrict__ out)
{
  // Fused embedding×W_ih0 tables: 100 rows × 32 gate-values, per-unit permuted:
  // sTf[row*32 + j*4 + q]  (q: 0=i,1=f,2=g,3=o for unit j) -> float4 per (row,j)
  __shared__ __align__(16) float sTf[3200];
  __shared__ float sW3s[65];   // sW3s[0]=0, sW3s[t+1]=fc3_w[t]  (deferred-FC weight)
  __shared__ __align__(16) float sH0[256];
  __shared__ __align__(16) float sH1[256];

  const int tid = threadIdx.x;

  // ---- build fused input tables in LDS ----
  {
    constexpr int RO[8]  = {0,2,4,25,47,52,54,76};
    constexpr int ED[8]  = {1,1,3,3,1,1,3,3};
    constexpr int CO[8]  = {0,1,2,5,8,9,10,13};
    constexpr int VOC[8] = {2,2,21,22,5,2,22,24};
    const float* ep[8] = {e1,e2,e3,e4,e5,e6,e7,e8};
    #pragma unroll
    for (int f = 0; f < 8; ++f) {
      const float* E = ep[f];
      for (int idx = tid; idx < VOC[f]*32; idx += 256) {
        int v = idx >> 5, m = idx & 31;
        int jj = m >> 2, q = m & 3, g = q*8 + jj;
        float s = 0.0f;
        #pragma unroll
        for (int d = 0; d < ED[f]; ++d)
          s += E[v*ED[f]+d] * W_ih0[g*16 + CO[f] + d];
        if (f == 0) s += b_ih0[g] + b_hh0[g];  // fold both biases into feat-0 table
        sTf[(RO[f]+v)*32 + m] = s;
      }
    }
    if (tid < 64) sW3s[tid+1] = fc3_w[tid];
    if (tid == 64) sW3s[0] = 0.f;
  }
  __syncthreads();

  const int j = tid & 7;                         // hidden unit owned by this lane
  const int b = (blockIdx.x << 5) + (tid >> 3);  // batch element

  sH1[tid] = 0.f;  // pre-init: read at top of t=0 before first write (in-wave ordering)

  // ---- per-lane recurrent weights packed as float2 (gate-pairs (i,f) and (g,o)) ----
  f2 wIF0[8], wGO0[8], iIF1[8], iGO1[8], rIF1[8], rGO1[8];
  {
    const float4* P;
    float4 I0,I1,F0,F1,G0_,G1_,O0,O1;
    #define LOADROWS(M) \
      P = (const float4*)(M); \
      I0 = P[(0*8+j)*2]; I1 = P[(0*8+j)*2+1]; \
      F0 = P[(1*8+j)*2]; F1 = P[(1*8+j)*2+1]; \
      G0_ = P[(2*8+j)*2]; G1_ = P[(2*8+j)*2+1]; \
      O0 = P[(3*8+j)*2]; O1 = P[(3*8+j)*2+1];
    #define PACK(dIF, dGO) \
      dIF[0]=(f2){I0.x,F0.x}; dIF[1]=(f2){I0.y,F0.y}; dIF[2]=(f2){I0.z,F0.z}; dIF[3]=(f2){I0.w,F0.w}; \
      dIF[4]=(f2){I1.x,F1.x}; dIF[5]=(f2){I1.y,F1.y}; dIF[6]=(f2){I1.z,F1.z}; dIF[7]=(f2){I1.w,F1.w}; \
      dGO[0]=(f2){G0_.x,O0.x}; dGO[1]=(f2){G0_.y,O0.y}; dGO[2]=(f2){G0_.z,O0.z}; dGO[3]=(f2){G0_.w,O0.w}; \
      dGO[4]=(f2){G1_.x,O1.x}; dGO[5]=(f2){G1_.y,O1.y}; dGO[6]=(f2){G1_.z,O1.z}; dGO[7]=(f2){G1_.w,O1.w};
    LOADROWS(W_hh0); PACK(wIF0, wGO0);
    LOADROWS(W_ih1); PACK(iIF1, iGO1);
    LOADROWS(W_hh1); PACK(rIF1, rGO1);
    #undef LOADROWS
    #undef PACK
  }
  const f2 bIF1 = {b_ih1[j]    + b_hh1[j],    b_ih1[8+j]  + b_hh1[8+j]};
  const f2 bGO1 = {b_ih1[16+j] + b_hh1[16+j], b_ih1[24+j] + b_hh1[24+j]};

  // ---- collapsed FC heads packed: thf = (theta, h) = sum_k uvk[k]*h1[k] + cc ----
  f2 uvk[8];
  float f7[4], f2c[4];
  #pragma unroll
  for (int q = 0; q < 4; ++q) { f7[q] = fc7_w[q]; f2c[q] = fc2_w[q]; }
  #pragma unroll
  for (int k = 0; k < 8; ++k) {
    float s1 = 0.f, s2 = 0.f;
    #pragma unroll
    for (int q = 0; q < 4; ++q) {
      s1 += f7[q]  * fc6_w[q*8+k];
      s2 += f2c[q] * fc1_w[q*8+k];
    }
    uvk[k] = (f2){s1, s2};
  }
  float cth = fc7_b[0], chh = fc2_b[0];
  #pragma unroll
  for (int q = 0; q < 4; ++q) { cth += f7[q]*fc6_b[q]; chh += f2c[q]*fc1_b[q]; }
  const f2 cc = {cth, chh};
  const float fc3b = fc3_b[0];

  // ---- state ----
  float h0s[8];
  #pragma unroll
  for (int k = 0; k < 8; ++k) h0s[k] = 0.f;
  float c0 = 0.f, c1 = 0.f, acc = 0.f;

  const int4* xp = (const int4*)(x + (size_t)b * 512);
  int4 ia = xp[0], ib = xp[1];
  const float4* tf4 = (const float4*)sTf;
  const float4* ph0 = (const float4*)&sH0[tid & ~7];
  const float4* ph1 = (const float4*)&sH1[tid & ~7];

  #pragma unroll 1
  for (int t = 0; t < 64; ++t) {
    // (1) issue read of h1(t-1) early — latency hides under gather + layer-0 work
    float4 h1A = ph1[0], h1B = ph1[1];
    float h1s[8] = {h1A.x,h1A.y,h1A.z,h1A.w,h1B.x,h1B.y,h1B.z,h1B.w};

    // (2) prefetch next step's ids
    const int tn = (t < 63) ? (2*t + 2) : 126;
    int4 na = xp[tn], nb = xp[tn+1];
    const float w3p = sW3s[t];   // FC of step t-1 folded into step t (0 at t=0)

    // (3) layer-0 input gates: gather fused-table rows (bias pre-folded)
    float4 g0 = tf4[(      ia.x)*8 + j];
    float4 g1 = tf4[(  2 + ia.y)*8 + j];
    float4 g2 = tf4[(  4 + ia.z)*8 + j];
    float4 g3 = tf4[( 25 + ia.w)*8 + j];
    float4 g4 = tf4[( 47 + ib.x)*8 + j];
    float4 g5 = tf4[( 52 + ib.y)*8 + j];
    float4 g6 = tf4[( 54 + ib.z)*8 + j];
    float4 g7 = tf4[( 76 + ib.w)*8 + j];
    f2 gIF = (((f2){g0.x,g0.y} + (f2){g1.x,g1.y}) + ((f2){g2.x,g2.y} + (f2){g3.x,g3.y}))
           + (((f2){g4.x,g4.y} + (f2){g5.x,g5.y}) + ((f2){g6.x,g6.y} + (f2){g7.x,g7.y}));
    f2 gGO = (((f2){g0.z,g0.w} + (f2){g1.z,g1.w}) + ((f2){g2.z,g2.w} + (f2){g3.z,g3.w}))
           + (((f2){g4.z,g4.w} + (f2){g5.z,g5.w}) + ((f2){g6.z,g6.w} + (f2){g7.z,g7.w}));

    // (4) layer-0 recurrence (packed), activations, write h0
    #pragma unroll
    for (int k = 0; k < 8; ++k) {
      f2 hb = (f2)(h0s[k]);
      gIF = __builtin_elementwise_fma(wIF0[k], hb, gIF);
      gGO = __builtin_elementwise_fma(wGO0[k], hb, gGO);
    }
    float si = sigf(gIF.x), sf = sigf(gIF.y), tg = tanh_fast(gGO.x), so = sigf(gGO.y);
    c0 = fmaf(sf, c0, si * tg);
    float h0 = so * tanh_fast(c0);
    sH0[tid] = h0;  // in-wave broadcast (8-lane groups never cross a wave)

    // (5) work independent of the h0 read: W_hh1*h1(t-1) and deferred FC(t-1)
    f2 GIF = bIF1, GGO = bGO1, thf = cc;
    #pragma unroll
    for (int k = 0; k < 8; ++k) {
      f2 hb = (f2)(h1s[k]);
      GIF = __builtin_elementwise_fma(rIF1[k], hb, GIF);
      GGO = __builtin_elementwise_fma(rGO1[k], hb, GGO);
      thf = __builtin_elementwise_fma(uvk[k],  hb, thf);
    }
    acc = fmaf(thf.x * thf.y, w3p, acc);

    // (6) read h0 back (exchange across the 8-lane group)
    {
      float4 lo = ph0[0], hi = ph0[1];
      h0s[0]=lo.x; h0s[1]=lo.y; h0s[2]=lo.z; h0s[3]=lo.w;
      h0s[4]=hi.x; h0s[5]=hi.y; h0s[6]=hi.z; h0s[7]=hi.w;
    }

    // (7) layer-1 input matvec, activations, write h1 (read deferred to t+1)
    #pragma unroll
    for (int k = 0; k < 8; ++k) {
      f2 hb = (f2)(h0s[k]);
      GIF = __builtin_elementwise_fma(iIF1[k], hb, GIF);
      GGO = __builtin_elementwise_fma(iGO1[k], hb, GGO);
    }
    float si1 = sigf(GIF.x), sf1 = sigf(GIF.y), tg1 = tanh_fast(GGO.x), so1 = sigf(GGO.y);
    c1 = fmaf(sf1, c1, si1 * tg1);
    float h1 = so1 * tanh_fast(c1);
    sH1[tid] = h1;

    ia = na; ib = nb;
  }

  // epilogue: FC for t=63
  {
    float4 h1A = ph1[0], h1B = ph1[1];
    float h1s[8] = {h1A.x,h1A.y,h1A.z,h1A.w,h1B.x,h1B.y,h1B.z,h1B.w};
    f2 thf = cc;
    #pragma unroll
    for (int k = 0; k < 8; ++k)
      thf = __builtin_elementwise_fma(uvk[k], (f2)(h1s[k]), thf);
    acc = fmaf(thf.x * thf.y, sW3s[64], acc);
  }

  if (j == 0) out[b] = acc + fc3b;
}

extern "C" void kernel_launch(void* const* d_in, const int* in_sizes, int n_in,
                              void* d_out, int out_size, void* d_ws, size_t ws_size,
                              hipStream_t stream) {
  const int* x = (const int*)d_in[0];
  const float *E1=(const float*)d_in[1],  *E2=(const float*)d_in[2],
              *E3=(const float*)d_in[3],  *E4=(const float*)d_in[4],
              *E5=(const float*)d_in[5],  *E6=(const float*)d_in[6],
              *E7=(const float*)d_in[7],  *E8=(const float*)d_in[8];
  const float *Wih0=(const float*)d_in[9],  *Whh0=(const float*)d_in[10],
              *bih0=(const float*)d_in[11], *bhh0=(const float*)d_in[12],
              *Wih1=(const float*)d_in[13], *Whh1=(const float*)d_in[14],
              *bih1=(const float*)d_in[15], *bhh1=(const float*)d_in[16],
              *fc6w=(const float*)d_in[17], *fc6b=(const float*)d_in[18],
              *fc7w=(const float*)d_in[19], *fc7b=(const float*)d_in[20],
              *fc1w=(const float*)d_in[21], *fc1b=(const float*)d_in[22],
              *fc2w=(const float*)d_in[23], *fc2b=(const float*)d_in[24],
              *fc3w=(const float*)d_in[25], *fc3b=(const float*)d_in[26];

  lstm_fused<<<512, 256, 0, stream>>>(
      x, E1,E2,E3,E4,E5,E6,E7,E8,
      Wih0, Whh0, bih0, bhh0, Wih1, Whh1, bih1, bhh1,
      fc6w, fc6b, fc7w, fc7b, fc1w, fc1b, fc2w, fc2b, fc3w, fc3b,
      (float*)d_out);
}